// Round 1
// 180.446 us; speedup vs baseline: 1.0087x; 1.0087x over previous
//
#include <hip/hip_runtime.h>
#include <hip/hip_bf16.h>

// out[b,c,hw] = sum_t x[b,t,c,hw] * W[c,t] + bias[c]
// B=16, T=10, C=1024, HW=196 (=49 float4s per map)
//
// R5 probe (from R4 @ 182.0us):
//  - k=2 batches per thread (b0, b0+8) instead of k=4: grid (196,8)=1568
//    blocks -> 24.5 waves/CU co-resident, finer granularity for block
//    scheduling balance; weight row still reused 2x.
//  - 32-bit offset arithmetic (max byte offset 128.45MB < 2^31) to cut
//    64-bit address VALU chains.
//  - nontemporal loads/stores kept (x read-once, out write-once).
// This is a disambiguation probe: if dur_us is unchanged (+-1.5us) the
// kernel share of dur_us is already at the 141.3MB/6.5TB/s streaming
// roofline and the remaining 153us is harness poison-fill; declare
// roofline next round.

#define T_IN      10
#define HW4       49
#define C_HW4     (1024 * HW4)      // 50176 float4s per (b,t) plane
#define B_STRIDE4 (T_IN * C_HW4)    // float4 stride between batches in x

typedef float f32x4 __attribute__((ext_vector_type(4)));

__global__ __launch_bounds__(256) void conv_over_time_kernel(
    const float* __restrict__ x,
    const float* __restrict__ Wmat,
    const float* __restrict__ bias,
    float* __restrict__ out)
{
    const int p4 = blockIdx.x * 256 + threadIdx.x;   // plane float4 offset [0, 50176)
    const int b0 = blockIdx.y;                       // [0, 8); handles b0 and b0+8
    const int c  = p4 / HW4;                         // magic-mul divide

    const f32x4* __restrict__ x4 = (const f32x4*)x;
    const float* __restrict__ wrow = Wmat + c * T_IN;

    float w[T_IN];
#pragma unroll
    for (int t = 0; t < T_IN; ++t) w[t] = wrow[t];

    const float bb = bias[c];
    f32x4 acc[2];
#pragma unroll
    for (int k = 0; k < 2; ++k) acc[k] = (f32x4){bb, bb, bb, bb};

    // 32-bit float4 offsets: max is 16*10*50176 = 8,028,160 < 2^31
    const int base0 = b0 * B_STRIDE4 + p4;           // batch b0
    const int base1 = base0 + 8 * B_STRIDE4;         // batch b0+8

#pragma unroll
    for (int t = 0; t < T_IN; ++t) {
        const int toff = t * C_HW4;
        const f32x4 v0 = __builtin_nontemporal_load(&x4[base0 + toff]);
        const f32x4 v1 = __builtin_nontemporal_load(&x4[base1 + toff]);
        acc[0].x = fmaf(v0.x, w[t], acc[0].x);
        acc[0].y = fmaf(v0.y, w[t], acc[0].y);
        acc[0].z = fmaf(v0.z, w[t], acc[0].z);
        acc[0].w = fmaf(v0.w, w[t], acc[0].w);
        acc[1].x = fmaf(v1.x, w[t], acc[1].x);
        acc[1].y = fmaf(v1.y, w[t], acc[1].y);
        acc[1].z = fmaf(v1.z, w[t], acc[1].z);
        acc[1].w = fmaf(v1.w, w[t], acc[1].w);
    }

    f32x4* __restrict__ out4 = (f32x4*)out;
    __builtin_nontemporal_store(acc[0], &out4[b0 * C_HW4 + p4]);
    __builtin_nontemporal_store(acc[1], &out4[(b0 + 8) * C_HW4 + p4]);
}

extern "C" void kernel_launch(void* const* d_in, const int* in_sizes, int n_in,
                              void* d_out, int out_size, void* d_ws, size_t ws_size,
                              hipStream_t stream) {
    const float* x    = (const float*)d_in[0];  // [16,10,1024,14,14]
    const float* Wmat = (const float*)d_in[1];  // [1024,10]
    const float* bias = (const float*)d_in[2];  // [1024]
    float* out = (float*)d_out;                 // [16,1,1024,14,14]

    dim3 grid(C_HW4 / 256, 8);                  // (196, 8)
    conv_over_time_kernel<<<grid, dim3(256), 0, stream>>>(x, Wmat, bias, out);
}